// Round 4
// baseline (356.833 us; speedup 1.0000x reference)
//
#include <hip/hip_runtime.h>

// Depthwise 3x3 conv, pad=1, stride=1, one shared 3x3 filter over all
// B*C=1024 planes of 224x224 fp32. Memory-bound (411 MB min HBM traffic,
// ~65us floor at 6.3 TB/s).
//
// Strategy: strip-mined rolling window. Each thread owns a 28-row x 4-col
// strip and slides a 3-row x 6-col register window down it:
//   - vertical read amplification 30/28 = 1.07x (vs 1.5x for 4x4 tiles)
//   - horizontal halo scalars hit the same 64B lines as neighboring lanes
//     (L1 hits, no extra HBM)
//   - nontemporal float4 stores keep the 205 MB write stream from evicting
//     input halo lines out of L2/L3.

#define HH 224
#define WW 224
#define X4T 56    // WW/4 float4 tiles per row
#define STRIPS 8
#define SH 28     // strip height (8*28 = 224)

typedef float f4 __attribute__((ext_vector_type(4)));

__device__ __forceinline__ void load_row6(float r[6], const float* rp,
                                          bool yok, bool xl, bool xr) {
    if (yok) {
        f4 v = *(const f4*)rp;            // aligned 16B load
        r[0] = xl ? rp[-1] : 0.f;         // left halo
        r[1] = v.x; r[2] = v.y; r[3] = v.z; r[4] = v.w;
        r[5] = xr ? rp[4] : 0.f;          // right halo
    } else {
        r[0] = r[1] = r[2] = r[3] = r[4] = r[5] = 0.f;
    }
}

__global__ __launch_bounds__(256) void dwconv3x3_strip(
    const float* __restrict__ X, const float* __restrict__ Wk,
    float* __restrict__ Out, int nThreads)
{
    int idx = blockIdx.x * 256 + threadIdx.x;
    if (idx >= nThreads) return;

    int x4    = idx % X4T;
    int t     = idx / X4T;
    int strip = t % STRIPS;
    int p     = t / STRIPS;

    // 9 shared weights — one cache line, broadcast from L1.
    const float w00 = Wk[0], w01 = Wk[1], w02 = Wk[2];
    const float w10 = Wk[3], w11 = Wk[4], w12 = Wk[5];
    const float w20 = Wk[6], w21 = Wk[7], w22 = Wk[8];

    const int  x0 = x4 * 4;
    const int  y0 = strip * SH;
    const bool xl = (x0 > 0);
    const bool xr = (x0 + 4 < WW);

    const float* plane  = X   + (size_t)p * (HH * WW) + x0;
    float*       oplane = Out + (size_t)p * (HH * WW) + x0;

    // Rolling 3-row window of 6 columns each.
    float a[6], b[6], c[6];
    load_row6(a, plane + (y0 - 1) * WW, y0 > 0, xl, xr);
    load_row6(b, plane + (y0    ) * WW, true,   xl, xr);

    #pragma unroll 4
    for (int j = 0; j < SH; ++j) {
        const int yn = y0 + j + 1;
        load_row6(c, plane + yn * WW, yn < HH, xl, xr);   // next row (overlaps compute)

        f4 o;
        #pragma unroll
        for (int ci = 0; ci < 4; ++ci) {
            float acc;
            acc  = w00 * a[ci] + w01 * a[ci + 1] + w02 * a[ci + 2];
            acc += w10 * b[ci] + w11 * b[ci + 1] + w12 * b[ci + 2];
            acc += w20 * c[ci] + w21 * c[ci + 1] + w22 * c[ci + 2];
            o[ci] = acc;
        }
        __builtin_nontemporal_store(o, (f4*)(oplane + (y0 + j) * WW));

        // rotate window (renamed away by unroll)
        #pragma unroll
        for (int q = 0; q < 6; ++q) { a[q] = b[q]; b[q] = c[q]; }
    }
}

extern "C" void kernel_launch(void* const* d_in, const int* in_sizes, int n_in,
                              void* d_out, int out_size, void* d_ws, size_t ws_size,
                              hipStream_t stream) {
    const float* X  = (const float*)d_in[0];
    const float* Wk = (const float*)d_in[1];
    float* Out = (float*)d_out;

    const int nPlanes  = 16 * 64;                        // B*C
    const int nThreads = nPlanes * STRIPS * X4T;         // 458,752
    const int threads  = 256;
    const int blocks   = (nThreads + threads - 1) / threads;  // 1792

    dwconv3x3_strip<<<blocks, threads, 0, stream>>>(X, Wk, Out, nThreads);
}

// Round 5
// 349.239 us; speedup vs baseline: 1.0217x; 1.0217x over previous
//
#include <hip/hip_runtime.h>

// Depthwise 3x3 conv, pad=1, stride=1, one shared 3x3 filter over all
// B*C=1024 planes of 224x224 fp32. Memory-bound: 411 MB min HBM traffic,
// ~65us floor at 6.3 TB/s.
//
// Round-4 post-mortem: rolling 1-row window => 1 outstanding load/wave
// (VGPR=28, VALUBusy 9.7%, 2.5 TB/s) — latency-bound. This version keeps
// the strip layout (1.07x vertical read amp) but processes 4 rows per
// batch with a one-batch-ahead prefetch double buffer: 4 independent
// 1KB wave-loads in flight, issued a full compute batch early.

#define HH 224
#define WW 224
#define X4T 56    // WW/4 float4 tiles per row
#define STRIPS 8
#define SH 28     // strip height (8*28 = 224)

typedef float f4 __attribute__((ext_vector_type(4)));

__device__ __forceinline__ void load_row6(float r[6], const float* rp,
                                          bool yok, bool xl, bool xr) {
    if (yok) {
        f4 v = *(const f4*)rp;            // aligned 16B load
        r[0] = xl ? rp[-1] : 0.f;         // left halo
        r[1] = v.x; r[2] = v.y; r[3] = v.z; r[4] = v.w;
        r[5] = xr ? rp[4] : 0.f;          // right halo
    } else {
        r[0] = r[1] = r[2] = r[3] = r[4] = r[5] = 0.f;
    }
}

__device__ __forceinline__ f4 conv3(const float a[6], const float b[6], const float c[6],
                                    float w00, float w01, float w02,
                                    float w10, float w11, float w12,
                                    float w20, float w21, float w22) {
    f4 o;
    #pragma unroll
    for (int ci = 0; ci < 4; ++ci) {
        float acc;
        acc  = w00 * a[ci] + w01 * a[ci + 1] + w02 * a[ci + 2];
        acc += w10 * b[ci] + w11 * b[ci + 1] + w12 * b[ci + 2];
        acc += w20 * c[ci] + w21 * c[ci + 1] + w22 * c[ci + 2];
        o[ci] = acc;
    }
    return o;
}

__global__ __launch_bounds__(256) void dwconv3x3_strip_pf(
    const float* __restrict__ X, const float* __restrict__ Wk,
    float* __restrict__ Out, int nThreads)
{
    int idx = blockIdx.x * 256 + threadIdx.x;
    if (idx >= nThreads) return;

    int x4    = idx % X4T;
    int t     = idx / X4T;
    int strip = t % STRIPS;
    int p     = t / STRIPS;

    const float w00 = Wk[0], w01 = Wk[1], w02 = Wk[2];
    const float w10 = Wk[3], w11 = Wk[4], w12 = Wk[5];
    const float w20 = Wk[6], w21 = Wk[7], w22 = Wk[8];

    const int  x0 = x4 * 4;
    const int  y0 = strip * SH;
    const bool xl = (x0 > 0);
    const bool xr = (x0 + 4 < WW);

    const float* plane  = X   + (size_t)p * (HH * WW) + x0;
    float*       oplane = Out + (size_t)p * (HH * WW) + x0;

    // Window rows: a = row j-1, b = row j, c[0..3] = rows j+1..j+4.
    // d is the prefetch buffer for the next batch.
    float a[6], b[6], c[4][6], d[4][6];

    load_row6(a, plane + (y0 - 1) * WW, y0 > 0, xl, xr);
    load_row6(b, plane + (y0    ) * WW, true,   xl, xr);
    #pragma unroll
    for (int q = 0; q < 4; ++q) {
        const int yn = y0 + 1 + q;
        load_row6(c[q], plane + yn * WW, yn < HH, xl, xr);
    }

    // Batches with prefetch: jb = 0,4,...,SH-8. Final batch peeled.
    #pragma unroll
    for (int jb = 0; jb < SH - 4; jb += 4) {
        // prefetch rows jb+5 .. jb+8 (independent of current compute)
        #pragma unroll
        for (int q = 0; q < 4; ++q) {
            const int yn = y0 + jb + 5 + q;
            load_row6(d[q], plane + yn * WW, yn < HH, xl, xr);
        }

        f4 o0 = conv3(a,    b,    c[0], w00,w01,w02,w10,w11,w12,w20,w21,w22);
        f4 o1 = conv3(b,    c[0], c[1], w00,w01,w02,w10,w11,w12,w20,w21,w22);
        f4 o2 = conv3(c[0], c[1], c[2], w00,w01,w02,w10,w11,w12,w20,w21,w22);
        f4 o3 = conv3(c[1], c[2], c[3], w00,w01,w02,w10,w11,w12,w20,w21,w22);

        __builtin_nontemporal_store(o0, (f4*)(oplane + (y0 + jb + 0) * WW));
        __builtin_nontemporal_store(o1, (f4*)(oplane + (y0 + jb + 1) * WW));
        __builtin_nontemporal_store(o2, (f4*)(oplane + (y0 + jb + 2) * WW));
        __builtin_nontemporal_store(o3, (f4*)(oplane + (y0 + jb + 3) * WW));

        // rotate window: new a = old c[2], new b = old c[3], c = d
        #pragma unroll
        for (int q = 0; q < 6; ++q) { a[q] = c[2][q]; b[q] = c[3][q]; }
        #pragma unroll
        for (int r = 0; r < 4; ++r)
            #pragma unroll
            for (int q = 0; q < 6; ++q) c[r][q] = d[r][q];
    }

    // final batch (rows SH-4 .. SH-1), no prefetch
    {
        const int jb = SH - 4;
        f4 o0 = conv3(a,    b,    c[0], w00,w01,w02,w10,w11,w12,w20,w21,w22);
        f4 o1 = conv3(b,    c[0], c[1], w00,w01,w02,w10,w11,w12,w20,w21,w22);
        f4 o2 = conv3(c[0], c[1], c[2], w00,w01,w02,w10,w11,w12,w20,w21,w22);
        f4 o3 = conv3(c[1], c[2], c[3], w00,w01,w02,w10,w11,w12,w20,w21,w22);

        __builtin_nontemporal_store(o0, (f4*)(oplane + (y0 + jb + 0) * WW));
        __builtin_nontemporal_store(o1, (f4*)(oplane + (y0 + jb + 1) * WW));
        __builtin_nontemporal_store(o2, (f4*)(oplane + (y0 + jb + 2) * WW));
        __builtin_nontemporal_store(o3, (f4*)(oplane + (y0 + jb + 3) * WW));
    }
}

extern "C" void kernel_launch(void* const* d_in, const int* in_sizes, int n_in,
                              void* d_out, int out_size, void* d_ws, size_t ws_size,
                              hipStream_t stream) {
    const float* X  = (const float*)d_in[0];
    const float* Wk = (const float*)d_in[1];
    float* Out = (float*)d_out;

    const int nPlanes  = 16 * 64;                        // B*C
    const int nThreads = nPlanes * STRIPS * X4T;         // 458,752
    const int threads  = 256;
    const int blocks   = (nThreads + threads - 1) / threads;  // 1792

    dwconv3x3_strip_pf<<<blocks, threads, 0, stream>>>(X, Wk, Out, nThreads);
}

// Round 8
// 349.036 us; speedup vs baseline: 1.0223x; 1.0006x over previous
//
#include <hip/hip_runtime.h>

// Depthwise 3x3 conv, pad=1, stride=1, one shared 3x3 filter over all
// B*C=1024 planes of 224x224 fp32. Memory-bound: ~320 MB effective HBM
// traffic (L3 absorbs part of X), ~51-65us floor.
//
// Round-5 post-mortem: MLP ladder — rolling window (128.6us) < 4-row dbuf
// with per-batch vmcnt(0) drain (123.5us) < fully-upfront loads (~92us, R1).
// This version: 8x4 tile per thread, ALL 30 loads (10 vec + 20 halo scalars,
// ~12.5KB/wave) issued before any FMA, zero mid-kernel drains, 5 block
// generations per CU for load-burst turnover, XCD-chunked block swizzle for
// halo L2 locality, nontemporal stores.

#define HH 224
#define WW 224
#define X4T 56    // WW/4 float4 tiles per row
#define YT  28    // 224/8 row-tiles
#define TH  8     // rows per thread

typedef float f4 __attribute__((ext_vector_type(4)));

__global__ __launch_bounds__(256) void dwconv3x3_8x4(
    const float* __restrict__ X, const float* __restrict__ Wk,
    float* __restrict__ Out)
{
    // XCD-chunked bijective swizzle (gridDim.x = 6272, 6272 % 8 == 0):
    // consecutive work chunks land on the same XCD -> halo rows L2-hit.
    const int nwg = gridDim.x;
    const int cpx = nwg >> 3;                       // chunks per XCD
    const int b   = blockIdx.x;
    const int wg  = (b & 7) * cpx + (b >> 3);

    const int idx = wg * 256 + (int)threadIdx.x;

    const int x4 = idx % X4T;
    const int t  = idx / X4T;
    const int ys = t % YT;
    const int p  = t / YT;

    const float w00 = Wk[0], w01 = Wk[1], w02 = Wk[2];
    const float w10 = Wk[3], w11 = Wk[4], w12 = Wk[5];
    const float w20 = Wk[6], w21 = Wk[7], w22 = Wk[8];

    const int  x0 = x4 * 4;
    const int  y0 = ys * TH;
    const bool xl = (x0 > 0);
    const bool xr = (x0 + 4 < WW);

    const float* plane  = X   + (size_t)p * (HH * WW) + x0;
    float*       oplane = Out + (size_t)p * (HH * WW) + x0;

    // All 10 input rows (y0-1 .. y0+8) x 6 cols loaded upfront — max MLP,
    // no dependent wait until compute, no mid-kernel vmcnt(0).
    float r[TH + 2][6];
    #pragma unroll
    for (int q = 0; q < TH + 2; ++q) {
        const int  yr  = y0 - 1 + q;
        const bool yok = (yr >= 0) && (yr < HH);
        const float* rp = plane + yr * WW;
        if (yok) {
            f4 v = *(const f4*)rp;
            r[q][0] = xl ? rp[-1] : 0.f;
            r[q][1] = v.x; r[q][2] = v.y; r[q][3] = v.z; r[q][4] = v.w;
            r[q][5] = xr ? rp[4] : 0.f;
        } else {
            r[q][0] = r[q][1] = r[q][2] = r[q][3] = r[q][4] = r[q][5] = 0.f;
        }
    }

    #pragma unroll
    for (int j = 0; j < TH; ++j) {
        f4 o;
        #pragma unroll
        for (int ci = 0; ci < 4; ++ci) {
            float acc;
            acc  = w00 * r[j+0][ci] + w01 * r[j+0][ci+1] + w02 * r[j+0][ci+2];
            acc += w10 * r[j+1][ci] + w11 * r[j+1][ci+1] + w12 * r[j+1][ci+2];
            acc += w20 * r[j+2][ci] + w21 * r[j+2][ci+1] + w22 * r[j+2][ci+2];
            o[ci] = acc;
        }
        __builtin_nontemporal_store(o, (f4*)(oplane + (y0 + j) * WW));
    }
}

extern "C" void kernel_launch(void* const* d_in, const int* in_sizes, int n_in,
                              void* d_out, int out_size, void* d_ws, size_t ws_size,
                              hipStream_t stream) {
    const float* X  = (const float*)d_in[0];
    const float* Wk = (const float*)d_in[1];
    float* Out = (float*)d_out;

    const int nPlanes  = 16 * 64;                    // B*C
    const int nThreads = nPlanes * YT * X4T;         // 1,605,632
    const int threads  = 256;
    const int blocks   = nThreads / threads;         // 6272 (exact, %8==0)

    dwconv3x3_8x4<<<blocks, threads, 0, stream>>>(X, Wk, Out);
}